// Round 4
// baseline (71.808 us; speedup 1.0000x reference)
//
#include <hip/hip_runtime.h>

// YoloLoss — fused single-pass reduction.
// R4: latency fix — grid-stride blocks + register prefetch of next tile's
// pred (issue-early / LDS-write-late), 128-thread blocks for cheap barriers
// and 8 blocks/CU residency.
// Inputs (setup_inputs order):
//   d_in[0] pred_tensor  f32 [NC, 30]
//   d_in[1] target_boxes f32 [NC, 4]
//   d_in[2] target_cls   f32 [NC, 20]
//   d_in[3] has_object_map int32 [NC]
// Output: d_out[0] = scalar loss (f32).

constexpr int TPB = 128;        // threads per block == cells per tile
constexpr int PRED_C = 30;
constexpr float EPSV = 1e-10f;

__device__ __forceinline__ float clamp01(float v) {
    return fminf(fmaxf(v, 0.0f), 1.0f);
}

__global__ __launch_bounds__(TPB, 4) void yolo_loss_kernel(
    const float* __restrict__ pred,
    const float* __restrict__ tbox,
    const float* __restrict__ tcls,
    const int* __restrict__ objmap,
    float* __restrict__ out,
    int ntiles, float inv_n)
{
    __shared__ float lds_pred[TPB * PRED_C];   // 15360 B
    __shared__ float lds_obj[TPB];             //   512 B
    __shared__ float wsum[2];

    const int t = threadIdx.x;
    const int stride = gridDim.x;
    int tile = blockIdx.x;

    float acc = 0.0f;

    // ---- prologue: stage first tile (pred -> LDS, obj -> LDS) ----
    {
        const float4* gp4 =
            reinterpret_cast<const float4*>(pred + (long long)tile * TPB * PRED_C);
        float4* lp4 = reinterpret_cast<float4*>(lds_pred);
        float4 pr[7];
        #pragma unroll
        for (int k = 0; k < 7; ++k) pr[k] = gp4[t + k * TPB];
        float4 pr7 = make_float4(0.f, 0.f, 0.f, 0.f);
        if (t < 64) pr7 = gp4[t + 7 * TPB];       // wave-uniform branch
        const int ob = objmap[(long long)tile * TPB + t];
        #pragma unroll
        for (int k = 0; k < 7; ++k) lp4[t + k * TPB] = pr[k];
        if (t < 64) lp4[t + 7 * TPB] = pr7;
        lds_obj[t] = ob ? 1.0f : 0.0f;
    }
    __syncthreads();

    while (true) {
        const int next = tile + stride;
        const bool has_next = next < ntiles;      // block-uniform

        // ---- issue next tile's loads NOW (latency hides under compute) ----
        float4 pr2[7];
        float4 pr27 = make_float4(0.f, 0.f, 0.f, 0.f);
        int ob2 = 0;
        if (has_next) {
            const float4* gp4 =
                reinterpret_cast<const float4*>(pred + (long long)next * TPB * PRED_C);
            #pragma unroll
            for (int k = 0; k < 7; ++k) pr2[k] = gp4[t + k * TPB];
            if (t < 64) pr27 = gp4[t + 7 * TPB];
            ob2 = objmap[(long long)next * TPB + t];
        }

        // ---- compute current tile ----
        const long long cell0 = (long long)tile * TPB;
        const float4 tb = reinterpret_cast<const float4*>(tbox)[cell0 + t];
        const float* P = lds_pred + t * PRED_C;
        const float objf = lds_obj[t];
        const float tx = tb.x, ty = tb.y, tw = tb.z, th = tb.w;

        const float invS = 1.0f / 14.0f;
        const float tcx = tx * invS, tcy = ty * invS;
        const float tww = fmaxf(tw, EPSV), thh = fmaxf(th, EPSV);
        const float tx1 = clamp01(tcx - 0.5f * tww);
        const float ty1 = clamp01(tcy - 0.5f * thh);
        const float tx2 = clamp01(tcx + 0.5f * tww);
        const float ty2 = clamp01(tcy + 0.5f * thh);
        const float tarea = (tx2 - tx1) * (ty2 - ty1);

        const float p0x = P[0], p0y = P[1], p0w = P[2], p0h = P[3], c0 = P[4];
        const float p1x = P[5], p1y = P[6], p1w = P[7], p1h = P[8], c1 = P[9];

        float iou0, iou1;
        {
            const float cx = p0x * invS, cy = p0y * invS;
            const float ww = fmaxf(p0w, EPSV), hh = fmaxf(p0h, EPSV);
            const float x1 = clamp01(cx - 0.5f * ww), y1 = clamp01(cy - 0.5f * hh);
            const float x2 = clamp01(cx + 0.5f * ww), y2 = clamp01(cy + 0.5f * hh);
            const float lx = fmaxf(x1, tx1), ly = fmaxf(y1, ty1);
            const float rx = fminf(x2, tx2), ry = fminf(y2, ty2);
            const float inter = fmaxf(rx - lx, 0.0f) * fmaxf(ry - ly, 0.0f);
            const float pa = (x2 - x1) * (y2 - y1);
            iou0 = inter / (pa + tarea - inter + EPSV);
        }
        {
            const float cx = p1x * invS, cy = p1y * invS;
            const float ww = fmaxf(p1w, EPSV), hh = fmaxf(p1h, EPSV);
            const float x1 = clamp01(cx - 0.5f * ww), y1 = clamp01(cy - 0.5f * hh);
            const float x2 = clamp01(cx + 0.5f * ww), y2 = clamp01(cy + 0.5f * hh);
            const float lx = fmaxf(x1, tx1), ly = fmaxf(y1, ty1);
            const float rx = fminf(x2, tx2), ry = fminf(y2, ty2);
            const float inter = fmaxf(rx - lx, 0.0f) * fmaxf(ry - ly, 0.0f);
            const float pa = (x2 - x1) * (y2 - y1);
            iou1 = inter / (pa + tarea - inter + EPSV);
        }

        const float d0 = c0 - 0.05f, d1 = c1 - 0.05f;
        const float noobj = (d0 * d0 + d1 * d1) * (1.0f - objf);

        const bool sel = iou1 > iou0;               // tie -> box 0
        const float biou = fminf((sel ? iou1 : iou0) + 0.5f, 0.95f);
        const float bx = sel ? p1x : p0x;
        const float by = sel ? p1y : p0y;
        const float bw = sel ? p1w : p0w;
        const float bh = sel ? p1h : p0h;
        const float bc = sel ? c1 : c0;

        const float spw = sqrtf(fabsf(bw) + 1e-6f);
        const float stw = sqrtf(fabsf(tw) + 1e-6f);
        const float sph = sqrtf(fabsf(bh) + 1e-6f);
        const float sth = sqrtf(fabsf(th) + 1e-6f);
        const float dx = bx - tx, dy = by - ty, dw = spw - stw, dh = sph - sth;
        const float reg = dx * dx + dy * dy + dw * dw + dh * dh;
        const float dcf = bc - biou;

        float tacc = noobj * 0.5f + (reg * 10.0f + dcf * dcf * 10.0f) * objf;

        // class BCE: bce = -ln2 * (lq + t*(lp-lq)), lp=log2(p), lq=log2(1-p)
        const float4* gtc4 = reinterpret_cast<const float4*>(tcls + cell0 * 20);
        float csum = 0.0f;
        #pragma unroll
        for (int k = 0; k < 5; ++k) {
            const int j4 = t + k * TPB;
            const int ci = j4 / 5;
            const int cc = (j4 - ci * 5) * 4;
            const float4 tv = gtc4[j4];
            const float* pp = lds_pred + ci * PRED_C + 10 + cc;
            const float of = lds_obj[ci];
            float s = 0.0f;
            const float tvv[4] = {tv.x, tv.y, tv.z, tv.w};
            #pragma unroll
            for (int u = 0; u < 4; ++u) {
                const float p = fminf(fmaxf(pp[u], 1e-7f), 1.0f - 1e-7f);
                const float lp = __log2f(p);
                const float lq = __log2f(1.0f - p);
                s += lq + tvv[u] * (lp - lq);
            }
            csum += s * of;
        }
        tacc += csum * (-0.5f * 0.69314718055994530942f);
        acc += tacc;

        if (!has_next) break;

        // ---- write-late: publish prefetched tile into LDS ----
        __syncthreads();                            // all done reading LDS
        {
            float4* lp4 = reinterpret_cast<float4*>(lds_pred);
            #pragma unroll
            for (int k = 0; k < 7; ++k) lp4[t + k * TPB] = pr2[k];
            if (t < 64) lp4[t + 7 * TPB] = pr27;
            lds_obj[t] = ob2 ? 1.0f : 0.0f;
        }
        __syncthreads();
        tile = next;
    }

    acc *= inv_n;

    // ---- reduction: wave shfl -> LDS -> one atomic per block ----
    #pragma unroll
    for (int off = 32; off > 0; off >>= 1) acc += __shfl_down(acc, off);
    if ((t & 63) == 0) wsum[t >> 6] = acc;
    __syncthreads();
    if (t == 0) atomicAdd(out, wsum[0] + wsum[1]);
}

extern "C" void kernel_launch(void* const* d_in, const int* in_sizes, int n_in,
                              void* d_out, int out_size, void* d_ws, size_t ws_size,
                              hipStream_t stream) {
    const float* pred = (const float*)d_in[0];
    const float* tbox = (const float*)d_in[1];
    const float* tcls = (const float*)d_in[2];
    const int* objmap = (const int*)d_in[3];
    float* out = (float*)d_out;

    const int ncells = in_sizes[3];          // N * S * S (802816)
    const int n_imgs = ncells / 196;         // N (4096)
    const float inv_n = 1.0f / (float)n_imgs;
    const int ntiles = ncells / TPB;         // 6272, exact

    // harness poisons d_out once and never re-poisons between replays
    hipMemsetAsync(out, 0, sizeof(float), stream);

    int grid = ntiles < 2048 ? ntiles : 2048;   // 8 blocks/CU, ~3 tiles each
    yolo_loss_kernel<<<grid, TPB, 0, stream>>>(pred, tbox, tcls, objmap, out,
                                               ntiles, inv_n);
}

// Round 5
// 65.225 us; speedup vs baseline: 1.1009x; 1.1009x over previous
//
#include <hip/hip_runtime.h>

// YoloLoss — fused single-pass reduction.
// R5: T14 pipeline with FIXED load ordering (current-tile reg loads issued
// BEFORE next-tile prefetch so vmcnt waits never drain the prefetch), and
// chunked-contiguous tile->block mapping for L3 locality.
// Inputs: pred f32[NC,30], tbox f32[NC,4], tcls f32[NC,20], objmap i32[NC].
// Output: d_out[0] = scalar loss (f32).

constexpr int TPB = 256;        // threads per block == cells per tile
constexpr int PRED_C = 30;
constexpr int CHUNK = 3;        // contiguous tiles per block
constexpr float EPSV = 1e-10f;

__device__ __forceinline__ float clamp01(float v) {
    return fminf(fmaxf(v, 0.0f), 1.0f);
}

__global__ __launch_bounds__(TPB, 4) void yolo_loss_kernel(
    const float* __restrict__ pred,
    const float* __restrict__ tbox,
    const float* __restrict__ tcls,
    const int* __restrict__ objmap,
    float* __restrict__ out,
    int ntiles, float inv_n)
{
    __shared__ float lds_pred[TPB * PRED_C];   // 30720 B
    __shared__ float lds_obj[TPB];             //  1024 B
    __shared__ float wsum[4];

    const int t = threadIdx.x;
    const int tile0 = blockIdx.x * CHUNK;      // grid sized so tile0 < ntiles
    const int tile_end = min(tile0 + CHUNK, ntiles);

    float acc = 0.0f;

    // ---- prologue: stage tile0 (pred -> LDS, obj -> LDS) ----
    {
        const float4* gp4 =
            reinterpret_cast<const float4*>(pred) + (size_t)tile0 * (TPB * PRED_C / 4);
        float4* lp4 = reinterpret_cast<float4*>(lds_pred);
        #pragma unroll
        for (int k = 0; k < 7; ++k) lp4[t + k * TPB] = gp4[t + k * TPB];
        if (t < TPB / 2) lp4[t + 7 * TPB] = gp4[t + 7 * TPB];
        lds_obj[t] = objmap[tile0 * TPB + t] ? 1.0f : 0.0f;
    }
    __syncthreads();

    for (int tile = tile0; tile < tile_end; ++tile) {
        const int cell0 = tile * TPB;

        // ---- 1) CURRENT tile's register loads — issued FIRST so their
        //         vmcnt waits leave the prefetch below outstanding ----
        const float4 tb = reinterpret_cast<const float4*>(tbox)[cell0 + t];
        float4 tv[5];                                   // tcls, coalesced j4 order
        {
            const float4* gtc4 =
                reinterpret_cast<const float4*>(tcls) + (size_t)cell0 * 5;
            #pragma unroll
            for (int k = 0; k < 5; ++k) tv[k] = gtc4[t + k * TPB];
        }

        // ---- 2) NEXT tile's prefetch (issue-early, write-late) ----
        const bool has_next = (tile + 1) < tile_end;    // block-uniform
        float4 pr2[7];
        float4 pr27 = make_float4(0.f, 0.f, 0.f, 0.f);
        int ob2 = 0;
        if (has_next) {
            const float4* gp4 = reinterpret_cast<const float4*>(pred) +
                                (size_t)(tile + 1) * (TPB * PRED_C / 4);
            #pragma unroll
            for (int k = 0; k < 7; ++k) pr2[k] = gp4[t + k * TPB];
            if (t < TPB / 2) pr27 = gp4[t + 7 * TPB];
            ob2 = objmap[cell0 + TPB + t];
        }

        // ---- 3) compute current tile ----
        const float* P = lds_pred + t * PRED_C;
        const float objf = lds_obj[t];
        const float tx = tb.x, ty = tb.y, tw = tb.z, th = tb.w;

        const float invS = 1.0f / 14.0f;
        const float tcx = tx * invS, tcy = ty * invS;
        const float tww = fmaxf(tw, EPSV), thh = fmaxf(th, EPSV);
        const float tx1 = clamp01(tcx - 0.5f * tww);
        const float ty1 = clamp01(tcy - 0.5f * thh);
        const float tx2 = clamp01(tcx + 0.5f * tww);
        const float ty2 = clamp01(tcy + 0.5f * thh);
        const float tarea = (tx2 - tx1) * (ty2 - ty1);

        const float p0x = P[0], p0y = P[1], p0w = P[2], p0h = P[3], c0 = P[4];
        const float p1x = P[5], p1y = P[6], p1w = P[7], p1h = P[8], c1 = P[9];

        float iou0, iou1;
        {
            const float cx = p0x * invS, cy = p0y * invS;
            const float ww = fmaxf(p0w, EPSV), hh = fmaxf(p0h, EPSV);
            const float x1 = clamp01(cx - 0.5f * ww), y1 = clamp01(cy - 0.5f * hh);
            const float x2 = clamp01(cx + 0.5f * ww), y2 = clamp01(cy + 0.5f * hh);
            const float lx = fmaxf(x1, tx1), ly = fmaxf(y1, ty1);
            const float rx = fminf(x2, tx2), ry = fminf(y2, ty2);
            const float inter = fmaxf(rx - lx, 0.0f) * fmaxf(ry - ly, 0.0f);
            const float pa = (x2 - x1) * (y2 - y1);
            iou0 = inter / (pa + tarea - inter + EPSV);
        }
        {
            const float cx = p1x * invS, cy = p1y * invS;
            const float ww = fmaxf(p1w, EPSV), hh = fmaxf(p1h, EPSV);
            const float x1 = clamp01(cx - 0.5f * ww), y1 = clamp01(cy - 0.5f * hh);
            const float x2 = clamp01(cx + 0.5f * ww), y2 = clamp01(cy + 0.5f * hh);
            const float lx = fmaxf(x1, tx1), ly = fmaxf(y1, ty1);
            const float rx = fminf(x2, tx2), ry = fminf(y2, ty2);
            const float inter = fmaxf(rx - lx, 0.0f) * fmaxf(ry - ly, 0.0f);
            const float pa = (x2 - x1) * (y2 - y1);
            iou1 = inter / (pa + tarea - inter + EPSV);
        }

        const float d0 = c0 - 0.05f, d1 = c1 - 0.05f;
        const float noobj = (d0 * d0 + d1 * d1) * (1.0f - objf);

        const bool sel = iou1 > iou0;                   // tie -> box 0
        const float biou = fminf((sel ? iou1 : iou0) + 0.5f, 0.95f);
        const float bx = sel ? p1x : p0x;
        const float by = sel ? p1y : p0y;
        const float bw = sel ? p1w : p0w;
        const float bh = sel ? p1h : p0h;
        const float bc = sel ? c1 : c0;

        const float spw = sqrtf(fabsf(bw) + 1e-6f);
        const float stw = sqrtf(fabsf(tw) + 1e-6f);
        const float sph = sqrtf(fabsf(bh) + 1e-6f);
        const float sth = sqrtf(fabsf(th) + 1e-6f);
        const float dx = bx - tx, dy = by - ty, dw = spw - stw, dh = sph - sth;
        const float reg = dx * dx + dy * dy + dw * dw + dh * dh;
        const float dcf = bc - biou;

        float tacc = noobj * 0.5f + (reg * 10.0f + dcf * dcf * 10.0f) * objf;

        // class BCE: bce = -ln2 * (lq + t*(lp-lq)), lp=log2(p), lq=log2(1-p)
        float csum = 0.0f;
        #pragma unroll
        for (int k = 0; k < 5; ++k) {
            const int j4 = t + k * TPB;
            const int ci = j4 / 5;
            const int cc = (j4 - ci * 5) * 4;
            const float* pp = lds_pred + ci * PRED_C + 10 + cc;
            const float of = lds_obj[ci];
            const float tvv[4] = {tv[k].x, tv[k].y, tv[k].z, tv[k].w};
            float s = 0.0f;
            #pragma unroll
            for (int u = 0; u < 4; ++u) {
                const float p = fminf(fmaxf(pp[u], 1e-7f), 1.0f - 1e-7f);
                const float lp = __log2f(p);
                const float lq = __log2f(1.0f - p);
                s += lq + tvv[u] * (lp - lq);
            }
            csum += s * of;
        }
        tacc += csum * (-0.5f * 0.69314718055994530942f);
        acc += tacc;

        // ---- 4) write-late: publish prefetched tile into LDS ----
        if (has_next) {
            __syncthreads();                            // all done reading LDS
            float4* lp4 = reinterpret_cast<float4*>(lds_pred);
            #pragma unroll
            for (int k = 0; k < 7; ++k) lp4[t + k * TPB] = pr2[k];
            if (t < TPB / 2) lp4[t + 7 * TPB] = pr27;
            lds_obj[t] = ob2 ? 1.0f : 0.0f;
            __syncthreads();
        }
    }

    acc *= inv_n;

    // ---- reduction: wave shfl -> LDS -> one atomic per block ----
    #pragma unroll
    for (int off = 32; off > 0; off >>= 1) acc += __shfl_down(acc, off);
    if ((t & 63) == 0) wsum[t >> 6] = acc;
    __syncthreads();
    if (t == 0) atomicAdd(out, wsum[0] + wsum[1] + wsum[2] + wsum[3]);
}

extern "C" void kernel_launch(void* const* d_in, const int* in_sizes, int n_in,
                              void* d_out, int out_size, void* d_ws, size_t ws_size,
                              hipStream_t stream) {
    const float* pred = (const float*)d_in[0];
    const float* tbox = (const float*)d_in[1];
    const float* tcls = (const float*)d_in[2];
    const int* objmap = (const int*)d_in[3];
    float* out = (float*)d_out;

    const int ncells = in_sizes[3];          // N * S * S (802816)
    const int n_imgs = ncells / 196;         // N (4096)
    const float inv_n = 1.0f / (float)n_imgs;
    const int ntiles = ncells / TPB;         // 3136, exact

    // harness poisons d_out once and never re-poisons between replays
    hipMemsetAsync(out, 0, sizeof(float), stream);

    const int grid = (ntiles + CHUNK - 1) / CHUNK;   // 1046 blocks, ~4/CU
    yolo_loss_kernel<<<grid, TPB, 0, stream>>>(pred, tbox, tcls, objmap, out,
                                               ntiles, inv_n);
}

// Round 6
// 35.895 us; speedup vs baseline: 2.0005x; 1.8171x over previous
//
#include <hip/hip_runtime.h>

// YoloLoss — R6: latency-bound fix via massive wave-level parallelism.
//  * 1-wave blocks (64 cells), 8 KB LDS -> 20 blocks/CU resident, no barrier
//    phase-locking; 12544 independent waves keep the memory queue full.
//  * pred tile staged via __builtin_amdgcn_global_load_lds (width 16, linear
//    dest = wave base + lane*16 which matches our layout exactly).
//  * current-tile tbox/tcls/obj register loads issued BEFORE the LDS DMA so
//    they complete inside the same vmcnt(0) drain -> compute is stall-free.
//  * NO same-address atomics: per-block partial -> d_ws, tiny 2nd kernel
//    reduces 12544 partials -> out. Deterministic, no memsets needed.
// Inputs: pred f32[NC,30], tbox f32[NC,4], tcls f32[NC,20], objmap i32[NC].
// Output: d_out[0] = scalar loss (f32).

constexpr int TPB = 64;         // one wave per block == cells per tile
constexpr int PRED_C = 30;
constexpr float EPSV = 1e-10f;

__device__ __forceinline__ float clamp01(float v) {
    return fminf(fmaxf(v, 0.0f), 1.0f);
}

// async global->LDS, 16B per active lane; LDS dst = wave-uniform base + lane*16
__device__ __forceinline__ void gl_lds16(const float4* g, float4* lds_base) {
    __builtin_amdgcn_global_load_lds(
        (const __attribute__((address_space(1))) void*)g,
        (__attribute__((address_space(3))) void*)lds_base, 16, 0, 0);
}

template <bool ATOMIC>
__global__ __launch_bounds__(TPB, 5) void yolo_part(
    const float* __restrict__ pred,
    const float* __restrict__ tbox,
    const float* __restrict__ tcls,
    const int* __restrict__ objmap,
    float* __restrict__ partial,     // ws path (ATOMIC=false)
    float* __restrict__ out,         // fallback path (ATOMIC=true)
    float inv_n)
{
    __shared__ float4 lds_p4[TPB * 8];   // 8192 B (480 used, 32 pad for DMA)
    __shared__ float lds_obj[TPB];

    const int t = threadIdx.x;
    const size_t tile = blockIdx.x;
    const size_t cell0 = tile * TPB;

    // ---- 1) current-tile register loads (oldest in vmcnt queue: they
    //         complete during the same drain as the LDS DMA below) ----
    const float4 tb = reinterpret_cast<const float4*>(tbox)[cell0 + t];
    float4 tv[5];                                    // tcls, coalesced j4 order
    {
        const float4* gtc4 = reinterpret_cast<const float4*>(tcls) + cell0 * 5;
        #pragma unroll
        for (int k = 0; k < 5; ++k) tv[k] = gtc4[t + k * TPB];
    }
    const int ob = objmap[cell0 + t];

    // ---- 2) pred tile -> LDS via async DMA (480 float4 = 64 lanes * 7.5) ----
    {
        const float4* gp4 = reinterpret_cast<const float4*>(pred) + tile * 480;
        #pragma unroll
        for (int k = 0; k < 7; ++k) gl_lds16(gp4 + t + k * 64, lds_p4 + k * 64);
        if (t < 32) gl_lds16(gp4 + t + 7 * 64, lds_p4 + 7 * 64);  // exec-masked
    }
    lds_obj[t] = ob ? 1.0f : 0.0f;
    __syncthreads();     // 1-wave block: vmcnt/lgkm drain, barrier trivial

    // ---- 3) per-cell box terms ----
    const float* lds_pred = reinterpret_cast<const float*>(lds_p4);
    const float* P = lds_pred + t * PRED_C;
    const float objf = lds_obj[t];
    const float tx = tb.x, ty = tb.y, tw = tb.z, th = tb.w;

    const float invS = 1.0f / 14.0f;
    const float tcx = tx * invS, tcy = ty * invS;
    const float tww = fmaxf(tw, EPSV), thh = fmaxf(th, EPSV);
    const float tx1 = clamp01(tcx - 0.5f * tww);
    const float ty1 = clamp01(tcy - 0.5f * thh);
    const float tx2 = clamp01(tcx + 0.5f * tww);
    const float ty2 = clamp01(tcy + 0.5f * thh);
    const float tarea = (tx2 - tx1) * (ty2 - ty1);

    const float p0x = P[0], p0y = P[1], p0w = P[2], p0h = P[3], c0 = P[4];
    const float p1x = P[5], p1y = P[6], p1w = P[7], p1h = P[8], c1 = P[9];

    float iou0, iou1;
    {
        const float cx = p0x * invS, cy = p0y * invS;
        const float ww = fmaxf(p0w, EPSV), hh = fmaxf(p0h, EPSV);
        const float x1 = clamp01(cx - 0.5f * ww), y1 = clamp01(cy - 0.5f * hh);
        const float x2 = clamp01(cx + 0.5f * ww), y2 = clamp01(cy + 0.5f * hh);
        const float lx = fmaxf(x1, tx1), ly = fmaxf(y1, ty1);
        const float rx = fminf(x2, tx2), ry = fminf(y2, ty2);
        const float inter = fmaxf(rx - lx, 0.0f) * fmaxf(ry - ly, 0.0f);
        const float pa = (x2 - x1) * (y2 - y1);
        iou0 = inter / (pa + tarea - inter + EPSV);
    }
    {
        const float cx = p1x * invS, cy = p1y * invS;
        const float ww = fmaxf(p1w, EPSV), hh = fmaxf(p1h, EPSV);
        const float x1 = clamp01(cx - 0.5f * ww), y1 = clamp01(cy - 0.5f * hh);
        const float x2 = clamp01(cx + 0.5f * ww), y2 = clamp01(cy + 0.5f * hh);
        const float lx = fmaxf(x1, tx1), ly = fmaxf(y1, ty1);
        const float rx = fminf(x2, tx2), ry = fminf(y2, ty2);
        const float inter = fmaxf(rx - lx, 0.0f) * fmaxf(ry - ly, 0.0f);
        const float pa = (x2 - x1) * (y2 - y1);
        iou1 = inter / (pa + tarea - inter + EPSV);
    }

    const float d0 = c0 - 0.05f, d1 = c1 - 0.05f;
    const float noobj = (d0 * d0 + d1 * d1) * (1.0f - objf);

    const bool sel = iou1 > iou0;                    // tie -> box 0
    const float biou = fminf((sel ? iou1 : iou0) + 0.5f, 0.95f);
    const float bx = sel ? p1x : p0x;
    const float by = sel ? p1y : p0y;
    const float bw = sel ? p1w : p0w;
    const float bh = sel ? p1h : p0h;
    const float bc = sel ? c1 : c0;

    const float spw = sqrtf(fabsf(bw) + 1e-6f);
    const float stw = sqrtf(fabsf(tw) + 1e-6f);
    const float sph = sqrtf(fabsf(bh) + 1e-6f);
    const float sth = sqrtf(fabsf(th) + 1e-6f);
    const float dx = bx - tx, dy = by - ty, dw = spw - stw, dh = sph - sth;
    const float reg = dx * dx + dy * dy + dw * dw + dh * dh;
    const float dcf = bc - biou;

    float acc = noobj * 0.5f + (reg * 10.0f + dcf * dcf * 10.0f) * objf;

    // ---- 4) class BCE: bce = -ln2*(lq + t*(lp-lq)), lp=log2(p), lq=log2(1-p)
    float csum = 0.0f;
    #pragma unroll
    for (int k = 0; k < 5; ++k) {
        const int j4 = t + k * TPB;
        const int ci = j4 / 5;
        const int cc = (j4 - ci * 5) * 4;
        const float* pp = lds_pred + ci * PRED_C + 10 + cc;
        const float of = lds_obj[ci];
        const float tvv[4] = {tv[k].x, tv[k].y, tv[k].z, tv[k].w};
        float s = 0.0f;
        #pragma unroll
        for (int u = 0; u < 4; ++u) {
            const float p = fminf(fmaxf(pp[u], 1e-7f), 1.0f - 1e-7f);
            const float lp = __log2f(p);
            const float lq = __log2f(1.0f - p);
            s += lq + tvv[u] * (lp - lq);
        }
        csum += s * of;
    }
    acc += csum * (-0.5f * 0.69314718055994530942f);

    // ---- 5) wave reduce, one plain store per block ----
    #pragma unroll
    for (int off = 32; off > 0; off >>= 1) acc += __shfl_down(acc, off);
    if (t == 0) {
        if (ATOMIC) atomicAdd(out, acc * inv_n);
        else partial[tile] = acc;
    }
}

__global__ __launch_bounds__(256) void yolo_reduce(
    const float* __restrict__ partial, float* __restrict__ out,
    int nblk4, float inv_n)
{
    __shared__ float ws[4];
    const int t = threadIdx.x;
    const float4* p4 = reinterpret_cast<const float4*>(partial);
    float s = 0.0f;
    for (int i = t; i < nblk4; i += 256) {
        const float4 v = p4[i];
        s += (v.x + v.y) + (v.z + v.w);
    }
    #pragma unroll
    for (int off = 32; off > 0; off >>= 1) s += __shfl_down(s, off);
    if ((t & 63) == 0) ws[t >> 6] = s;
    __syncthreads();
    if (t == 0) out[0] = (ws[0] + ws[1] + ws[2] + ws[3]) * inv_n;
}

extern "C" void kernel_launch(void* const* d_in, const int* in_sizes, int n_in,
                              void* d_out, int out_size, void* d_ws, size_t ws_size,
                              hipStream_t stream) {
    const float* pred = (const float*)d_in[0];
    const float* tbox = (const float*)d_in[1];
    const float* tcls = (const float*)d_in[2];
    const int* objmap = (const int*)d_in[3];
    float* out = (float*)d_out;

    const int ncells = in_sizes[3];          // N * S * S (802816)
    const int n_imgs = ncells / 196;         // N (4096)
    const float inv_n = 1.0f / (float)n_imgs;
    const int nblk = ncells / TPB;           // 12544, exact

    if (ws_size >= (size_t)nblk * sizeof(float)) {
        float* partial = (float*)d_ws;
        yolo_part<false><<<nblk, TPB, 0, stream>>>(pred, tbox, tcls, objmap,
                                                   partial, nullptr, inv_n);
        yolo_reduce<<<1, 256, 0, stream>>>(partial, out, nblk / 4, inv_n);
    } else {
        // fallback if workspace too small: atomic accumulate (zero out first)
        hipMemsetAsync(out, 0, sizeof(float), stream);
        yolo_part<true><<<nblk, TPB, 0, stream>>>(pred, tbox, tcls, objmap,
                                                  nullptr, out, inv_n);
    }
}

// Round 7
// 35.040 us; speedup vs baseline: 2.0493x; 1.0244x over previous
//
#include <hip/hip_runtime.h>

// YoloLoss — R7: R6 structure (1-wave blocks, LDS-DMA, no atomics) +
//  * all BCE LDS reads hoisted into registers before the log2 chain (ILP),
//  * lds_obj removed (obj via __shfl: tile == one wave, cell == lane),
//  * LDS trimmed to 7680 B -> ~21 blocks/CU,
//  * 1024-thread reduce kernel for the tail.
// Inputs: pred f32[NC,30], tbox f32[NC,4], tcls f32[NC,20], objmap i32[NC].
// Output: d_out[0] = scalar loss (f32).

constexpr int TPB = 64;         // one wave per block == cells per tile
constexpr float EPSV = 1e-10f;

__device__ __forceinline__ float clamp01(float v) {
    return fminf(fmaxf(v, 0.0f), 1.0f);
}

// async global->LDS, 16B per active lane; LDS dst = wave-uniform base + lane*16
__device__ __forceinline__ void gl_lds16(const float4* g, float4* lds_base) {
    __builtin_amdgcn_global_load_lds(
        (const __attribute__((address_space(1))) void*)g,
        (__attribute__((address_space(3))) void*)lds_base, 16, 0, 0);
}

template <bool ATOMIC>
__global__ __launch_bounds__(TPB, 6) void yolo_part(
    const float* __restrict__ pred,
    const float* __restrict__ tbox,
    const float* __restrict__ tcls,
    const int* __restrict__ objmap,
    float* __restrict__ partial,     // ws path (ATOMIC=false)
    float* __restrict__ out,         // fallback path (ATOMIC=true)
    float inv_n)
{
    __shared__ float4 lds_p4[TPB * 15 / 2];   // 480 float4 = 7680 B exactly

    const int t = threadIdx.x;
    const size_t tile = blockIdx.x;
    const size_t cell0 = tile * TPB;

    // ---- 1) current-tile register loads (oldest in vmcnt queue) ----
    const float4 tb = reinterpret_cast<const float4*>(tbox)[cell0 + t];
    float4 tv[5];                                    // tcls, coalesced j4 order
    {
        const float4* gtc4 = reinterpret_cast<const float4*>(tcls) + cell0 * 5;
        #pragma unroll
        for (int k = 0; k < 5; ++k) tv[k] = gtc4[t + k * TPB];
    }
    const int ob = objmap[cell0 + t];

    // ---- 2) pred tile -> LDS via async DMA (480 float4) ----
    {
        const float4* gp4 = reinterpret_cast<const float4*>(pred) + tile * 480;
        #pragma unroll
        for (int k = 0; k < 7; ++k) gl_lds16(gp4 + t + k * 64, lds_p4 + k * 64);
        if (t < 32) gl_lds16(gp4 + t + 7 * 64, lds_p4 + 7 * 64);  // exec-masked
    }
    __syncthreads();     // 1-wave block: vmcnt drain + trivial barrier

    const float2* lds2 = reinterpret_cast<const float2*>(lds_p4);
    const float objf = ob ? 1.0f : 0.0f;

    // ---- 3) burst-load own-cell box part (10 floats as 5 float2) ----
    float2 pb[5];
    #pragma unroll
    for (int q = 0; q < 5; ++q) pb[q] = lds2[t * 15 + q];

    // ---- 3b) burst-load cross-cell BCE operands (20 floats as 10 float2) ----
    float2 pcl[10];
    int cis[5];
    #pragma unroll
    for (int k = 0; k < 5; ++k) {
        const int j4 = t + k * TPB;
        const int ci = j4 / 5;
        const int r  = j4 - ci * 5;
        cis[k] = ci;
        const int b2 = ci * 15 + 5 + 2 * r;   // (ci*30 + 10 + 4r)/2, 8B-aligned
        pcl[2 * k]     = lds2[b2];
        pcl[2 * k + 1] = lds2[b2 + 1];
    }

    // ---- 4) per-cell box terms (all operands now in registers) ----
    const float tx = tb.x, ty = tb.y, tw = tb.z, th = tb.w;
    const float invS = 1.0f / 14.0f;
    const float tcx = tx * invS, tcy = ty * invS;
    const float tww = fmaxf(tw, EPSV), thh = fmaxf(th, EPSV);
    const float tx1 = clamp01(tcx - 0.5f * tww);
    const float ty1 = clamp01(tcy - 0.5f * thh);
    const float tx2 = clamp01(tcx + 0.5f * tww);
    const float ty2 = clamp01(tcy + 0.5f * thh);
    const float tarea = (tx2 - tx1) * (ty2 - ty1);

    const float p0x = pb[0].x, p0y = pb[0].y, p0w = pb[1].x, p0h = pb[1].y;
    const float c0  = pb[2].x;
    const float p1x = pb[2].y, p1y = pb[3].x, p1w = pb[3].y, p1h = pb[4].x;
    const float c1  = pb[4].y;

    float iou0, iou1;
    {
        const float cx = p0x * invS, cy = p0y * invS;
        const float ww = fmaxf(p0w, EPSV), hh = fmaxf(p0h, EPSV);
        const float x1 = clamp01(cx - 0.5f * ww), y1 = clamp01(cy - 0.5f * hh);
        const float x2 = clamp01(cx + 0.5f * ww), y2 = clamp01(cy + 0.5f * hh);
        const float lx = fmaxf(x1, tx1), ly = fmaxf(y1, ty1);
        const float rx = fminf(x2, tx2), ry = fminf(y2, ty2);
        const float inter = fmaxf(rx - lx, 0.0f) * fmaxf(ry - ly, 0.0f);
        const float pa = (x2 - x1) * (y2 - y1);
        iou0 = inter / (pa + tarea - inter + EPSV);
    }
    {
        const float cx = p1x * invS, cy = p1y * invS;
        const float ww = fmaxf(p1w, EPSV), hh = fmaxf(p1h, EPSV);
        const float x1 = clamp01(cx - 0.5f * ww), y1 = clamp01(cy - 0.5f * hh);
        const float x2 = clamp01(cx + 0.5f * ww), y2 = clamp01(cy + 0.5f * hh);
        const float lx = fmaxf(x1, tx1), ly = fmaxf(y1, ty1);
        const float rx = fminf(x2, tx2), ry = fminf(y2, ty2);
        const float inter = fmaxf(rx - lx, 0.0f) * fmaxf(ry - ly, 0.0f);
        const float pa = (x2 - x1) * (y2 - y1);
        iou1 = inter / (pa + tarea - inter + EPSV);
    }

    const float d0 = c0 - 0.05f, d1 = c1 - 0.05f;
    const float noobj = (d0 * d0 + d1 * d1) * (1.0f - objf);

    const bool sel = iou1 > iou0;                    // tie -> box 0
    const float biou = fminf((sel ? iou1 : iou0) + 0.5f, 0.95f);
    const float bx = sel ? p1x : p0x;
    const float by = sel ? p1y : p0y;
    const float bw = sel ? p1w : p0w;
    const float bh = sel ? p1h : p0h;
    const float bc = sel ? c1 : c0;

    const float spw = sqrtf(fabsf(bw) + 1e-6f);
    const float stw = sqrtf(fabsf(tw) + 1e-6f);
    const float sph = sqrtf(fabsf(bh) + 1e-6f);
    const float sth = sqrtf(fabsf(th) + 1e-6f);
    const float dx = bx - tx, dy = by - ty, dw = spw - stw, dh = sph - sth;
    const float reg = dx * dx + dy * dy + dw * dw + dh * dh;
    const float dcf = bc - biou;

    float acc = noobj * 0.5f + (reg * 10.0f + dcf * dcf * 10.0f) * objf;

    // ---- 5) class BCE from registers: -ln2*(lq + t*(lp-lq)) ----
    float csum = 0.0f;
    #pragma unroll
    for (int k = 0; k < 5; ++k) {
        const float of = __shfl(objf, cis[k]);       // obj of cell cis[k]
        const float pv[4] = {pcl[2 * k].x, pcl[2 * k].y,
                             pcl[2 * k + 1].x, pcl[2 * k + 1].y};
        const float tvv[4] = {tv[k].x, tv[k].y, tv[k].z, tv[k].w};
        float s = 0.0f;
        #pragma unroll
        for (int u = 0; u < 4; ++u) {
            const float p = fminf(fmaxf(pv[u], 1e-7f), 1.0f - 1e-7f);
            const float lp = __log2f(p);
            const float lq = __log2f(1.0f - p);
            s += lq + tvv[u] * (lp - lq);
        }
        csum += s * of;
    }
    acc += csum * (-0.5f * 0.69314718055994530942f);

    // ---- 6) wave reduce, one plain store per block ----
    #pragma unroll
    for (int off = 32; off > 0; off >>= 1) acc += __shfl_down(acc, off);
    if (t == 0) {
        if (ATOMIC) atomicAdd(out, acc * inv_n);
        else partial[tile] = acc;
    }
}

__global__ __launch_bounds__(1024) void yolo_reduce(
    const float* __restrict__ partial, float* __restrict__ out,
    int nblk4, float inv_n)
{
    __shared__ float ws[16];
    const int t = threadIdx.x;
    const float4* p4 = reinterpret_cast<const float4*>(partial);
    float s = 0.0f;
    for (int i = t; i < nblk4; i += 1024) {
        const float4 v = p4[i];
        s += (v.x + v.y) + (v.z + v.w);
    }
    #pragma unroll
    for (int off = 32; off > 0; off >>= 1) s += __shfl_down(s, off);
    if ((t & 63) == 0) ws[t >> 6] = s;
    __syncthreads();
    if (t < 16) {
        s = ws[t];
        #pragma unroll
        for (int off = 8; off > 0; off >>= 1) s += __shfl_down(s, off, 16);
        if (t == 0) out[0] = s * inv_n;
    }
}

extern "C" void kernel_launch(void* const* d_in, const int* in_sizes, int n_in,
                              void* d_out, int out_size, void* d_ws, size_t ws_size,
                              hipStream_t stream) {
    const float* pred = (const float*)d_in[0];
    const float* tbox = (const float*)d_in[1];
    const float* tcls = (const float*)d_in[2];
    const int* objmap = (const int*)d_in[3];
    float* out = (float*)d_out;

    const int ncells = in_sizes[3];          // N * S * S (802816)
    const int n_imgs = ncells / 196;         // N (4096)
    const float inv_n = 1.0f / (float)n_imgs;
    const int nblk = ncells / TPB;           // 12544, exact

    if (ws_size >= (size_t)nblk * sizeof(float)) {
        float* partial = (float*)d_ws;
        yolo_part<false><<<nblk, TPB, 0, stream>>>(pred, tbox, tcls, objmap,
                                                   partial, nullptr, inv_n);
        yolo_reduce<<<1, 1024, 0, stream>>>(partial, out, nblk / 4, inv_n);
    } else {
        // fallback if workspace too small: atomic accumulate (zero out first)
        hipMemsetAsync(out, 0, sizeof(float), stream);
        yolo_part<true><<<nblk, TPB, 0, stream>>>(pred, tbox, tcls, objmap,
                                                  nullptr, out, inv_n);
    }
}